// Round 8
// baseline (324.331 us; speedup 1.0000x reference)
//
#include <hip/hip_runtime.h>
#include <math.h>

// Problem constants
#define B_   4
#define S_   2048
#define D_   1024
#define H_   1024
#define NROW 2048
#define TOTX 8388608.0f            // B_*S_*D_ elements of x

typedef _Float16 f16x8 __attribute__((ext_vector_type(8)));
typedef float f32x4 __attribute__((ext_vector_type(4)));
typedef unsigned short us8 __attribute__((ext_vector_type(8)));

__device__ __forceinline__ unsigned short f2h(float f) {
  _Float16 h = (_Float16)f;                       // v_cvt_f16_f32, RNE
  return __builtin_bit_cast(unsigned short, h);
}
__device__ __forceinline__ float h2f(unsigned short u) {
  return (float)__builtin_bit_cast(_Float16, u);  // v_cvt_f32_f16
}

// async global->LDS, 16B per lane, lands at ldsbase + lane*16
#define GLD16(gp, lp)                                                            \
  __builtin_amdgcn_global_load_lds(                                              \
      (__attribute__((address_space(1))) void*)(gp),                             \
      (__attribute__((address_space(3))) void*)(lp), 16, 0, 0)

// ---------------------------------------------------------------------------
// fused float->f16 conversion + abs-sum for x (one pass over 32 MB)
// ---------------------------------------------------------------------------
__global__ __launch_bounds__(256) void f2h_abs_kernel(const float* __restrict__ in,
                                                      unsigned short* __restrict__ out,
                                                      float* absOut, int n4) {
  int i0 = blockIdx.x * 256 + threadIdx.x;
  int stride = gridDim.x * 256;
  float s = 0.f;
  for (int i = i0; i < n4; i += stride) {
    float4 v = ((const float4*)in)[i];
    ushort4 o;
    o.x = f2h(v.x); o.y = f2h(v.y); o.z = f2h(v.z); o.w = f2h(v.w);
    ((ushort4*)out)[i] = o;
    s += fabsf(v.x) + fabsf(v.y) + fabsf(v.z) + fabsf(v.w);
  }
#pragma unroll
  for (int off = 32; off; off >>= 1) s += __shfl_xor(s, off);
  __shared__ float red[4];
  if ((threadIdx.x & 63) == 0) red[threadIdx.x >> 6] = s;
  __syncthreads();
  if (threadIdx.x == 0) atomicAdd(absOut, red[0] + red[1] + red[2] + red[3]);
}

// ---------------------------------------------------------------------------
// three weight matrices -> f16 in one launch (blockIdx.y selects matrix)
// ---------------------------------------------------------------------------
__global__ __launch_bounds__(256) void f2h3_kernel(const float* __restrict__ a,
                                                   const float* __restrict__ b,
                                                   const float* __restrict__ c,
                                                   unsigned short* __restrict__ oa,
                                                   unsigned short* __restrict__ ob,
                                                   unsigned short* __restrict__ oc,
                                                   int n4) {
  int i = blockIdx.x * 256 + threadIdx.x;
  if (i >= n4) return;
  const float* in = (blockIdx.y == 0) ? a : (blockIdx.y == 1) ? b : c;
  unsigned short* out = (blockIdx.y == 0) ? oa : (blockIdx.y == 1) ? ob : oc;
  float4 v = ((const float4*)in)[i];
  ushort4 o;
  o.x = f2h(v.x); o.y = f2h(v.y); o.z = f2h(v.z); o.w = f2h(v.w);
  ((ushort4*)out)[i] = o;
}

// ---------------------------------------------------------------------------
// 8-phase-style f16 MFMA GEMM NT, 256x256 tile (MI=8), BK=32, 8 waves,
// triple-buffered LDS (96 KB), launch_bounds(512,1) -> ~190 VGPR, 2 waves/SIMD
// (the validated 256^2 template's occupancy). Per K-tile, TWO phases at the
// template's 1-barrier-per-16-MFMA density:
//  A: {ds_read af0-3,bf0-3 | 2 GLDs for t+2 -> bar -> lgkm0 -> prio1 ->
//      16 MFMA -> prio0 -> bar}
//  B: {ds_read af4-7 | 2 GLDs -> bar -> lgkm0 -> prio1 -> 16 MFMA -> prio0 ->
//      vmcnt(4) -> bar}
// FIFO: at the vmcnt(4), outstanding = t+1's 4 (oldest) + t+2's 4 (newest);
// vmcnt(4) guarantees t+1 landed while t+2 stays in flight (T4: never 0).
// WAR-safe: buffer (t+2)%3 was last read at t-1, drained at t-1's lgkm0.
// Optional V^T epilogue (blockIdx.z==2): acc's 4 consecutive-m values form a
// ushort4 of the transposed [b][H][S] layout directly.
// ---------------------------------------------------------------------------
template <bool OUT_F16>
__global__ __launch_bounds__(512, 1) void gemm8p_nt(const unsigned short* __restrict__ A,
                                                    const unsigned short* __restrict__ B,
                                                    void* __restrict__ Cv,
                                                    unsigned short* __restrict__ VT,
                                                    int M, int N, int K,
                                                    long long sA, long long sB, long long sC,
                                                    float scale) {
  constexpr int ASZ = 256 * 32;         // u16 per A tile
  constexpr int TSZ = 2 * ASZ;          // u16 per buffer (A+B) = 32 KB

  const int bz = blockIdx.z;
  A += (long long)bz * sA;
  B += (long long)bz * sB;

  __shared__ __align__(16) unsigned short lds[3 * TSZ];   // 96 KB

  const int tid = threadIdx.x;
  const int lane = tid & 63;
  const int w = tid >> 6;
  const int wr = w >> 2;          // 0..1 : 128-row band
  const int wc = w & 3;           // 0..3 : 64-col band
  const int m0 = blockIdx.y * 256, n0 = blockIdx.x * 256;

  f32x4 acc[8][4] = {};

  // staging: 512 threads, lane l of wave w -> row tid>>2 (0..127), chunk swizzle
  const int srow = tid >> 2;
  const int scol = ((lane & 3) ^ ((lane >> 3) & 3)) * 8;
  const unsigned short* gA0 = A + (long long)(m0 + srow) * K + scol;
  const unsigned short* gA1 = gA0 + (long long)128 * K;
  const unsigned short* gB0 = B + (long long)(n0 + srow) * K + scol;
  const unsigned short* gB1 = gB0 + (long long)128 * K;
  const int wb = w * 512;

  // fragment read offsets (u16 units), same swizzle family as staging
  const int fm = lane & 15;
  const int col8 = ((lane >> 4) ^ ((lane >> 1) & 3)) * 8;
  int aoff[8], boff[4];
#pragma unroll
  for (int mi = 0; mi < 8; ++mi) aoff[mi] = (wr * 128 + mi * 16 + fm) * 32 + col8;
#pragma unroll
  for (int ni = 0; ni < 4; ++ni) boff[ni] = ASZ + (wc * 64 + ni * 16 + fm) * 32 + col8;

  const int nt = K >> 5;

#define STAGE4(Lp, k0)                                   \
  do {                                                   \
    GLD16(gA0 + (k0), (Lp) + wb);                        \
    GLD16(gA1 + (k0), (Lp) + 4096 + wb);                 \
    GLD16(gB0 + (k0), (Lp) + ASZ + wb);                  \
    GLD16(gB1 + (k0), (Lp) + ASZ + 4096 + wb);           \
  } while (0)

  unsigned short* L0 = lds;
  unsigned short* L1 = lds + TSZ;
  unsigned short* L2 = lds + 2 * TSZ;

  // prologue: tile0 -> buf0, tile1 -> buf1; wait tile0 (tile1 in flight)
  STAGE4(L0, 0);
  STAGE4(L1, 32);
  asm volatile("s_waitcnt vmcnt(4)" ::: "memory");
  __builtin_amdgcn_s_barrier();

  for (int t = 0; t < nt; ++t) {
    const bool st = (t + 2 < nt);
    const int k2 = (t + 2) << 5;

    // ---- phase A ----
    f16x8 af[4], bf[4];
#pragma unroll
    for (int mi = 0; mi < 4; ++mi) af[mi] = *(const f16x8*)(L0 + aoff[mi]);
#pragma unroll
    for (int ni = 0; ni < 4; ++ni) bf[ni] = *(const f16x8*)(L0 + boff[ni]);
    if (st) { GLD16(gA0 + k2, L2 + wb); GLD16(gA1 + k2, L2 + 4096 + wb); }
    __builtin_amdgcn_s_barrier();
    asm volatile("s_waitcnt lgkmcnt(0)" ::: "memory");
    __builtin_amdgcn_sched_barrier(0);
    __builtin_amdgcn_s_setprio(1);
#pragma unroll
    for (int mi = 0; mi < 4; ++mi)
#pragma unroll
      for (int ni = 0; ni < 4; ++ni)
        acc[mi][ni] = __builtin_amdgcn_mfma_f32_16x16x32_f16(af[mi], bf[ni],
                                                             acc[mi][ni], 0, 0, 0);
    __builtin_amdgcn_s_setprio(0);
    __builtin_amdgcn_s_barrier();

    // ---- phase B ----
    f16x8 ag[4];
#pragma unroll
    for (int mi = 0; mi < 4; ++mi) ag[mi] = *(const f16x8*)(L0 + aoff[4 + mi]);
    if (st) { GLD16(gB0 + k2, L2 + ASZ + wb); GLD16(gB1 + k2, L2 + ASZ + 4096 + wb); }
    __builtin_amdgcn_s_barrier();
    asm volatile("s_waitcnt lgkmcnt(0)" ::: "memory");
    __builtin_amdgcn_sched_barrier(0);
    __builtin_amdgcn_s_setprio(1);
#pragma unroll
    for (int mi = 0; mi < 4; ++mi)
#pragma unroll
      for (int ni = 0; ni < 4; ++ni)
        acc[4 + mi][ni] = __builtin_amdgcn_mfma_f32_16x16x32_f16(ag[mi], bf[ni],
                                                                 acc[4 + mi][ni], 0, 0, 0);
    __builtin_amdgcn_s_setprio(0);
    if (st)               asm volatile("s_waitcnt vmcnt(4)" ::: "memory");
    else if (t + 1 < nt)  asm volatile("s_waitcnt vmcnt(0)" ::: "memory");
    __builtin_amdgcn_s_barrier();
    unsigned short* tmp = L0; L0 = L1; L1 = L2; L2 = tmp;
  }
#undef STAGE4

  // epilogue: C/D layout col=lane&15, row=(lane>>4)*4+reg
  const int cm = (lane >> 4) * 4;
  const int cn = lane & 15;
  if (VT != nullptr && bz == 2) {
#pragma unroll
    for (int mi = 0; mi < 8; ++mi)
#pragma unroll
      for (int ni = 0; ni < 4; ++ni) {
        int m = m0 + wr * 128 + mi * 16 + cm;
        int n = n0 + wc * 64 + ni * 16 + cn;
        int b = m >> 11, s = m & 2047;
        ushort4 o;
        o.x = f2h(acc[mi][ni][0] * scale);
        o.y = f2h(acc[mi][ni][1] * scale);
        o.z = f2h(acc[mi][ni][2] * scale);
        o.w = f2h(acc[mi][ni][3] * scale);
        *(ushort4*)(VT + (long long)b * (H_ * S_) + (long long)n * S_ + s) = o;
      }
    return;
  }
#pragma unroll
  for (int mi = 0; mi < 8; ++mi)
#pragma unroll
    for (int ni = 0; ni < 4; ++ni) {
#pragma unroll
      for (int r = 0; r < 4; ++r) {
        long long m = m0 + wr * 128 + mi * 16 + cm + r;
        long long n = n0 + wc * 64 + ni * 16 + cn;
        float v = acc[mi][ni][r] * scale;
        if (OUT_F16)
          ((unsigned short*)Cv)[(long long)bz * sC + m * N + n] = f2h(v);
        else
          ((float*)Cv)[(long long)bz * sC + m * N + n] = v;
      }
    }
}

// ---------------------------------------------------------------------------
// f16 MFMA GEMM NT (round-7 single-barrier triple-buffer), MI=4 (128x256),
// used for PV (256 blocks, 2 blocks/CU).
// ---------------------------------------------------------------------------
template <int MI, bool OUT_F16>
__global__ __launch_bounds__(512, 2) void gemm8_nt(const unsigned short* __restrict__ A,
                                                   const unsigned short* __restrict__ B,
                                                   void* __restrict__ Cv,
                                                   unsigned short* __restrict__ VT,
                                                   int M, int N, int K,
                                                   long long sA, long long sB, long long sC,
                                                   float scale) {
  constexpr int BM  = MI * 32;
  constexpr int ASZ = BM * 32;
  constexpr int BSZ = 256 * 32;
  constexpr int TSZ = ASZ + BSZ;

  const int bz = blockIdx.z;
  A += (long long)bz * sA;
  B += (long long)bz * sB;

  __shared__ __align__(16) unsigned short lds[3 * TSZ];

  const int tid = threadIdx.x;
  const int lane = tid & 63;
  const int w = tid >> 6;
  const int wr = w >> 2;
  const int wc = w & 3;
  const int m0 = blockIdx.y * BM, n0 = blockIdx.x * 256;

  f32x4 acc[MI][4] = {};

  const int srow = tid >> 2;
  const int scol = ((lane & 3) ^ ((lane >> 3) & 3)) * 8;
  const unsigned short* gA0 = A + (long long)(m0 + srow) * K + scol;
  const unsigned short* gA1 = gA0 + (long long)128 * K;   // MI==8 only
  const unsigned short* gB0 = B + (long long)(n0 + srow) * K + scol;
  const unsigned short* gB1 = gB0 + (long long)128 * K;
  const int wb = w * 512;

  const int fm = lane & 15;
  const int col8 = ((lane >> 4) ^ ((lane >> 1) & 3)) * 8;
  int aoff[MI], boff[4];
#pragma unroll
  for (int mi = 0; mi < MI; ++mi) aoff[mi] = (wr * (MI * 16) + mi * 16 + fm) * 32 + col8;
#pragma unroll
  for (int ni = 0; ni < 4; ++ni) boff[ni] = ASZ + (wc * 64 + ni * 16 + fm) * 32 + col8;

  const int nt = K >> 5;

#define STAGEP(Lp, k0)                                   \
  do {                                                   \
    GLD16(gA0 + (k0), (Lp) + wb);                        \
    if (MI == 8) GLD16(gA1 + (k0), (Lp) + 4096 + wb);    \
    GLD16(gB0 + (k0), (Lp) + ASZ + wb);                  \
    GLD16(gB1 + (k0), (Lp) + ASZ + 4096 + wb);           \
  } while (0)

  unsigned short* L0 = lds;
  unsigned short* L1 = lds + TSZ;
  unsigned short* L2 = lds + 2 * TSZ;

  STAGEP(L0, 0);
  STAGEP(L1, 32);
  if (MI == 8) asm volatile("s_waitcnt vmcnt(4)" ::: "memory");
  else         asm volatile("s_waitcnt vmcnt(3)" ::: "memory");
  __builtin_amdgcn_s_barrier();

  for (int t = 0; t < nt; ++t) {
    f16x8 af[MI], bf[4];
#pragma unroll
    for (int mi = 0; mi < MI; ++mi) af[mi] = *(const f16x8*)(L0 + aoff[mi]);
#pragma unroll
    for (int ni = 0; ni < 4; ++ni) bf[ni] = *(const f16x8*)(L0 + boff[ni]);
    if (t + 2 < nt) STAGEP(L2, (t + 2) << 5);
    asm volatile("s_waitcnt lgkmcnt(0)" ::: "memory");
    __builtin_amdgcn_sched_barrier(0);
    __builtin_amdgcn_s_setprio(1);
#pragma unroll
    for (int mi = 0; mi < MI; ++mi)
#pragma unroll
      for (int ni = 0; ni < 4; ++ni)
        acc[mi][ni] = __builtin_amdgcn_mfma_f32_16x16x32_f16(af[mi], bf[ni],
                                                             acc[mi][ni], 0, 0, 0);
    __builtin_amdgcn_s_setprio(0);
    if (t + 2 < nt) {
      if (MI == 8) asm volatile("s_waitcnt vmcnt(4)" ::: "memory");
      else         asm volatile("s_waitcnt vmcnt(3)" ::: "memory");
    } else if (t + 1 < nt) {
      asm volatile("s_waitcnt vmcnt(0)" ::: "memory");
    }
    __builtin_amdgcn_s_barrier();
    unsigned short* tmp = L0; L0 = L1; L1 = L2; L2 = tmp;
  }
#undef STAGEP

  const int cm = (lane >> 4) * 4;
  const int cn = lane & 15;
  if (VT != nullptr && bz == 2) {
#pragma unroll
    for (int mi = 0; mi < MI; ++mi)
#pragma unroll
      for (int ni = 0; ni < 4; ++ni) {
        int m = m0 + wr * (MI * 16) + mi * 16 + cm;
        int n = n0 + wc * 64 + ni * 16 + cn;
        int b = m >> 11, s = m & 2047;
        ushort4 o;
        o.x = f2h(acc[mi][ni][0] * scale);
        o.y = f2h(acc[mi][ni][1] * scale);
        o.z = f2h(acc[mi][ni][2] * scale);
        o.w = f2h(acc[mi][ni][3] * scale);
        *(ushort4*)(VT + (long long)b * (H_ * S_) + (long long)n * S_ + s) = o;
      }
    return;
  }
#pragma unroll
  for (int mi = 0; mi < MI; ++mi)
#pragma unroll
    for (int ni = 0; ni < 4; ++ni) {
#pragma unroll
      for (int r = 0; r < 4; ++r) {
        long long m = m0 + wr * (MI * 16) + mi * 16 + cm + r;
        long long n = n0 + wc * 64 + ni * 16 + cn;
        float v = acc[mi][ni][r] * scale;
        if (OUT_F16)
          ((unsigned short*)Cv)[(long long)bz * sC + m * N + n] = f2h(v);
        else
          ((float*)Cv)[(long long)bz * sC + m * N + n] = v;
      }
    }
}

// ---------------------------------------------------------------------------
// Wave-per-row sparsemax/softmax on f16 scores (round-7, known-good, 83 us).
// ---------------------------------------------------------------------------
template <int K, int J>
__device__ __forceinline__ void intra_s(float (&r)[32]) {
#pragma unroll
  for (int v = 0; v < 32; ++v)
    if ((v & J) == 0) {
      const int u = v | J;
      const bool dsc = ((v & K) == 0);
      float a = r[v], b = r[u];
      float mx = fmaxf(a, b), mn = fminf(a, b);
      r[v] = dsc ? mx : mn;
      r[u] = dsc ? mn : mx;
    }
}

template <int J>
__device__ __forceinline__ void intra_desc(float (&r)[32]) {
#pragma unroll
  for (int v = 0; v < 32; ++v)
    if ((v & J) == 0) {
      const int u = v | J;
      float a = r[v], b = r[u];
      r[v] = fmaxf(a, b);
      r[u] = fminf(a, b);
    }
}

template <int JL>
__device__ __forceinline__ void cross_desc(float (&r)[32], int lane, int bp32) {
  const bool keepmax = ((lane & JL) == 0);
  float b[32];
#pragma unroll
  for (int v = 0; v < 32; ++v) {
    int av = __builtin_bit_cast(int, r[v]);
    int bv;
    if constexpr (JL == 32)
      bv = __builtin_amdgcn_ds_bpermute(bp32, av);
    else
      bv = __builtin_amdgcn_ds_swizzle(av, (JL << 10) | 0x1F);  // xor-mode
    b[v] = __builtin_bit_cast(float, bv);
  }
  __builtin_amdgcn_sched_barrier(0);   // pin: all swizzles issued before CEs
#pragma unroll
  for (int v = 0; v < 32; ++v) {
    float mx = fmaxf(r[v], b[v]), mn = fminf(r[v], b[v]);
    r[v] = keepmax ? mx : mn;
  }
}

__device__ __forceinline__ void signfix(float (&r)[32], unsigned fix) {
#pragma unroll
  for (int v = 0; v < 32; ++v)
    r[v] = __builtin_bit_cast(float, __builtin_bit_cast(unsigned, r[v]) ^ fix);
}

__global__ __launch_bounds__(256, 4) void attn_row_wave(const unsigned short* __restrict__ scores,
                                                        unsigned short* __restrict__ attn,
                                                        const float* __restrict__ absSum) {
  const int tid = threadIdx.x;
  const int lane = tid & 63;
  const int row = blockIdx.x * 4 + (tid >> 6);
  const unsigned short* rowp = scores + (long long)row * NROW;
  unsigned short* aout = attn + (long long)row * NROW;
  const int bp32 = (lane ^ 32) << 2;

  // per-lane contiguous 64B chunk of f16 scores: element e = lane*32 + v
  const us8* rp = (const us8*)(rowp + lane * 32);
  float r[32];
  float lm = -INFINITY, lsraw = 0.f;
#pragma unroll
  for (int q = 0; q < 4; ++q) {
    us8 h = rp[q];
#pragma unroll
    for (int j = 0; j < 8; ++j) {
      float f = h2f((unsigned short)h[j]);
      r[q * 8 + j] = f;
      lm = fmaxf(lm, f);
      lsraw += f;
    }
  }
#pragma unroll
  for (int off = 32; off; off >>= 1) {
    lm = fmaxf(lm, __shfl_xor(lm, off, 64));
    lsraw += __shfl_xor(lsraw, off, 64);
  }

  const bool use_softmax = (absSum[0] * (1.0f / TOTX)) >= 1.0f;

  if (use_softmax) {
    float ls = 0.f;
#pragma unroll
    for (int v = 0; v < 32; ++v) { r[v] = expf(r[v] - lm); ls += r[v]; }
#pragma unroll
    for (int off = 32; off; off >>= 1) ls += __shfl_xor(ls, off, 64);
    float inv = 1.0f / ls;
    us8* op = (us8*)(aout + lane * 32);
#pragma unroll
    for (int q = 0; q < 4; ++q) {
      us8 o;
#pragma unroll
      for (int j = 0; j < 8; ++j) o[j] = f2h(r[q * 8 + j] * inv);
      op[q] = o;
    }
    return;
  }

  // ---- sparsemax ----
#pragma unroll
  for (int v = 0; v < 32; ++v) r[v] -= lm;
  const float step = ((lsraw - (float)NROW * lm) - 1.0f) * (1.0f / (float)NROW);

  // per-lane bitonic presort (compile-time directions)
  intra_s<2, 1>(r);
  intra_s<4, 2>(r); intra_s<4, 1>(r);
  intra_s<8, 4>(r); intra_s<8, 2>(r); intra_s<8, 1>(r);
  intra_s<16, 8>(r); intra_s<16, 4>(r); intra_s<16, 2>(r); intra_s<16, 1>(r);

  // merge ladder with running sign mask (negate-on-!dsc => all merges desc)
  unsigned cur = (unsigned)(lane & 1) << 31;               // kl=1
  signfix(r, cur);
  intra_desc<16>(r); intra_desc<8>(r); intra_desc<4>(r);
  intra_desc<2>(r); intra_desc<1>(r);

  { unsigned want = (unsigned)(lane & 2) << 30;            // kl=2
    signfix(r, cur ^ want); cur = want; }
  cross_desc<1>(r, lane, bp32);
  intra_desc<16>(r); intra_desc<8>(r); intra_desc<4>(r);
  intra_desc<2>(r); intra_desc<1>(r);

  { unsigned want = (unsigned)(lane & 4) << 29;            // kl=4
    signfix(r, cur ^ want); cur = want; }
  cross_desc<2>(r, lane, bp32); cross_desc<1>(r, lane, bp32);
  intra_desc<16>(r); intra_desc<8>(r); intra_desc<4>(r);
  intra_desc<2>(r); intra_desc<1>(r);

  { unsigned want = (unsigned)(lane & 8) << 28;            // kl=8
    signfix(r, cur ^ want); cur = want; }
  cross_desc<4>(r, lane, bp32); cross_desc<2>(r, lane, bp32);
  cross_desc<1>(r, lane, bp32);
  intra_desc<16>(r); intra_desc<8>(r); intra_desc<4>(r);
  intra_desc<2>(r); intra_desc<1>(r);

  { unsigned want = (unsigned)(lane & 16) << 27;           // kl=16
    signfix(r, cur ^ want); cur = want; }
  cross_desc<8>(r, lane, bp32); cross_desc<4>(r, lane, bp32);
  cross_desc<2>(r, lane, bp32); cross_desc<1>(r, lane, bp32);
  intra_desc<16>(r); intra_desc<8>(r); intra_desc<4>(r);
  intra_desc<2>(r); intra_desc<1>(r);

  { unsigned want = (unsigned)(lane & 32) << 26;           // kl=32
    signfix(r, cur ^ want); cur = want; }
  cross_desc<16>(r, lane, bp32); cross_desc<8>(r, lane, bp32);
  cross_desc<4>(r, lane, bp32); cross_desc<2>(r, lane, bp32);
  cross_desc<1>(r, lane, bp32);
  intra_desc<16>(r); intra_desc<8>(r); intra_desc<4>(r);
  intra_desc<2>(r); intra_desc<1>(r);

  signfix(r, cur);                                         // kl=64: dsc==true everywhere
  cross_desc<32>(r, lane, bp32); cross_desc<16>(r, lane, bp32);
  cross_desc<8>(r, lane, bp32); cross_desc<4>(r, lane, bp32);
  cross_desc<2>(r, lane, bp32); cross_desc<1>(r, lane, bp32);
  intra_desc<16>(r); intra_desc<8>(r); intra_desc<4>(r);
  intra_desc<2>(r); intra_desc<1>(r);

  // k = count(sorted > step)
  float lcnt = 0.f;
#pragma unroll
  for (int v = 0; v < 32; ++v) lcnt += (r[v] > step) ? 1.0f : 0.0f;
#pragma unroll
  for (int off = 32; off; off >>= 1) lcnt += __shfl_xor(lcnt, off, 64);
  const float kf = lcnt;

  // inclusive cumsum over e: local sequential + wave scan of lane totals
  float run = 0.f;
#pragma unroll
  for (int v = 0; v < 32; ++v) { run += r[v]; r[v] = run; }
  float pre = run;
#pragma unroll
  for (int off = 1; off < 64; off <<= 1) {
    float t = __shfl_up(pre, off, 64);
    if (lane >= off) pre += t;
  }
  pre -= run;  // exclusive prefix of lane totals
#pragma unroll
  for (int v = 0; v < 32; ++v) r[v] += pre;

  const float inv_k = 1.0f / kf;
  const float c1 = 1.0f + step * kf;

  // epilogue: re-read original f16 z through a laundered pointer (blocks CSE)
  unsigned long long up = (unsigned long long)rowp;
  asm volatile("" : "+v"(up));
  const us8* rpe = (const us8*)up + lane * 4;
  us8* op = (us8*)(aout + lane * 32);
#pragma unroll
  for (int q = 0; q < 4; ++q) {
    us8 h = rpe[q];
    us8 o;
#pragma unroll
    for (int j = 0; j < 8; ++j) {
      float z = h2f((unsigned short)h[j]) - lm;
      o[j] = f2h(fmaxf(z - (r[q * 8 + j] - c1) * inv_k, 0.0f));
    }
    op[q] = o;
  }
}

// ---------------------------------------------------------------------------
extern "C" void kernel_launch(void* const* d_in, const int* in_sizes, int n_in,
                              void* d_out, int out_size, void* d_ws, size_t ws_size,
                              hipStream_t stream) {
  const float* x  = (const float*)d_in[0];
  const float* Wq = (const float*)d_in[1];
  const float* Wk = (const float*)d_in[2];
  const float* Wv = (const float*)d_in[3];
  float* out = (float*)d_out;

  const long long NX = (long long)B_ * S_ * D_;   // 8M
  const long long NW = (long long)H_ * D_;        // 1M

  // Workspace layout (total 144 MB + 4 B):
  //  [0,16MB):    x16          -> later Sc16 (f16 scores, 32MB, overwrites x16+W)
  //  [16,22MB):   Wq16 Wk16 Wv16 (contiguous, 2MB apart -> fused proj)
  //  [64,80MB):   Vt16 (written directly by proj epilogue; persists to PV)
  //  [80,96MB):   Q16   [96,112MB): K16
  //  [80,112MB):  A16 (f16 attention, 32MB; overwrites Q16/K16 after scores)
  //  [144MB]:     flag
  char* base = (char*)d_ws;
  unsigned short* x16  = (unsigned short*)(base);
  unsigned short* Wq16 = (unsigned short*)(base + (16ll << 20));
  unsigned short* Wk16 = (unsigned short*)(base + (18ll << 20));
  unsigned short* Wv16 = (unsigned short*)(base + (20ll << 20));
  unsigned short* Sc16 = (unsigned short*)(base);
  unsigned short* Vt16 = (unsigned short*)(base + (64ll << 20));
  unsigned short* Q16  = (unsigned short*)(base + (80ll << 20));
  unsigned short* K16  = (unsigned short*)(base + (96ll << 20));
  unsigned short* A16  = (unsigned short*)(base + (80ll << 20));
  float*          flag = (float*)(base + (144ll << 20));

  hipMemsetAsync(flag, 0, sizeof(float), stream);

  // fused x->f16 + abs-sum (grid-stride)
  f2h_abs_kernel<<<1024, 256, 0, stream>>>(x, x16, flag, (int)(NX / 4));
  // W -> f16, one launch
  f2h3_kernel<<<dim3((int)(NW / 4 + 255) / 256, 3), 256, 0, stream>>>(
      Wq, Wk, Wv, Wq16, Wk16, Wv16, (int)(NW / 4));

  // Projections fused (8-phase 256^2): z selects W (stride 1M) and output
  // (stride 8M elems); z==2 (V) writes transposed [b][H][S] via VT epilogue.
  // grid 4 x 32 x 3 = 384 blocks
  {
    dim3 grid(H_ / 256, (B_ * S_) / 256, 3);
    gemm8p_nt<true><<<grid, 512, 0, stream>>>(x16, Wq16, Q16, Vt16,
                                              B_ * S_, H_, D_,
                                              0, (long long)NW, (long long)(8ll << 20),
                                              1.0f);
  }

  // scores = Q @ K^T / 32 (8-phase 256^2, f16 out; overwrites x16/W)
  // grid 8 x 8 x 4 = 256 blocks = exactly 1/CU
  {
    dim3 grid(S_ / 256, S_ / 256, B_);
    gemm8p_nt<true><<<grid, 512, 0, stream>>>(Q16, K16, Sc16, nullptr,
                                              S_, S_, H_,
                                              (long long)S_ * H_, (long long)S_ * H_,
                                              (long long)S_ * S_, 1.0f / 32.0f);
  }

  // attention = sparsemax-or-softmax(scores) -> f16 (one wave per row)
  attn_row_wave<<<(B_ * S_) / 4, 256, 0, stream>>>(Sc16, A16, flag);

  // out = attention @ Vt^T (MI=4 single-barrier kernel), fp32 out
  // grid 4 x 16 x 4 = 256 blocks, 2 blocks/CU
  {
    dim3 grid(H_ / 256, S_ / 128, B_);
    gemm8_nt<4, false><<<grid, 512, 0, stream>>>(A16, Vt16, out, nullptr,
                                                 S_, H_, S_,
                                                 (long long)S_ * S_, (long long)H_ * S_,
                                                 (long long)S_ * H_, 1.0f);
  }
}